// Round 7
// baseline (599.443 us; speedup 1.0000x reference)
//
#include <hip/hip_runtime.h>

// ---------------------------------------------------------------------------
// 2-layer GCN forward, 12-launch pipeline.
// prepW -> front(hist+gemm1) -> scan1 -> scan2 -> place -> degsort(+deg hist)
// -> dscan -> dperm -> ew -> gather128 -> gemm2 -> gather40.
// r11: XCD-resident feature slicing, H1 SLICE-MAJOR [8][n][8]u32 (3.2MB/slice
//      < 4MB per-XCD L2); slice = blockIdx&7. PROVEN: FETCH 283->75MB.
// r12/r13: subgroup-per-node, broadcast edge loads, packed 15-bit weights,
//      8-deep software pipeline (97us, best sliced variant).
// r15 lesson: LDS-atomic push = op-count wall. r16 lesson: glds+shfl in the
//      address path costs more than the dest-VGPR serialization it removes.
// r17: DEGREE-SORTED NODE SCHEDULING. r13's loop runs max(deg) over the
//      wave's 8 subgroup-nodes with idle subgroups masked: E[max of 8] ~ 25
//      vs mean 16 = ~1.5x wasted batches + ragged wave lifetimes (occ 75%).
//      Counting-sort nodes by degree (hist in degsort, 1-block scan, block
//      place) and process node = perm[idx] in both gathers -> uniform trip
//      counts, balanced retirement. Numerics unchanged (order only).
// ---------------------------------------------------------------------------

typedef unsigned int u32;
typedef unsigned short u16;
typedef __attribute__((ext_vector_type(8))) short short8;
typedef __attribute__((ext_vector_type(4))) float floatx4;

#define CHUNK 4096            // edges per histogram/place block

#define REP7(M)  M(0) M(1) M(2) M(3) M(4) M(5) M(6)
#define REP8(M)  M(0) M(1) M(2) M(3) M(4) M(5) M(6) M(7)

static __device__ inline u16 f2bf(float f) {
    u32 u = __float_as_uint(f);
    return (u16)((u + 0x7FFFu + ((u >> 16) & 1u)) >> 16);   // RNE
}
static __device__ inline u32 pack2(float a, float b) {
    return (u32)f2bf(a) | ((u32)f2bf(b) << 16);
}
static __device__ inline float bflo(u32 u) { return __uint_as_float(u << 16); }
static __device__ inline float bfhi(u32 u) { return __uint_as_float(u & 0xffff0000u); }

// wave-local int64-vs-int32 storage detection: sample 64 odd int32 slots of
// the first 64 index values; all-zero => int64 (high words), else int32.
static __device__ inline bool detect_is64(const int* e32, int lane) {
    bool nz = e32[2 * lane + 1] != 0;
    return __ballot(nz) == 0ull;
}

// ---- W1 -> WTb bf16; W2 -> W2Tb bf16 (zero-pad); zero 256-bin deg hist -----
__global__ void k_prepW(const float* __restrict__ W1, const float* __restrict__ W2,
                        u16* __restrict__ WTb, u16* __restrict__ W2Tb,
                        int* __restrict__ dHist) {
    int id = blockIdx.x * 256 + threadIdx.x;
    if (id < 16384) {
        int k = id >> 7, c = id & 127;           // W1[k][c]
        WTb[c * 128 + k] = f2bf(W1[id]);
    } else if (id < 22528) {
        int id2 = id - 16384;                    // 48 x 128, zero-pad cols 40+
        int c = id2 >> 7, k = id2 & 127;
        W2Tb[id2] = f2bf(c < 40 ? W2[k * 40 + c] : 0.f);
    } else if (id < 22784) {
        dHist[id - 22528] = 0;
    }
}

// ---- fused front: blocks [0,NC) = per-chunk bucket histogram,
//      blocks [NC, NC+G1) = GEMM1 (MFMA, unscaled bf16 out, slice-major) ----
__global__ __launch_bounds__(256) void k_front(const void* __restrict__ e_raw,
                                               int E, int NC, int NB,
                                               int* __restrict__ histG,
                                               const float* __restrict__ X,
                                               const u16* __restrict__ WTb,
                                               u16* __restrict__ H1s, int n) {
    __shared__ u32 smem[64 * 68 + 128 * 68];     // 52,224 B, shared by roles
    const int tid = threadIdx.x;
    if ((int)blockIdx.x < NC) {
        // ---------- histogram role ----------
        int* h = (int*)smem;
        h[tid] = 0; h[tid + 256] = 0;
        __syncthreads();
        const int* e32 = (const int*)e_raw;
        bool is64 = detect_is64(e32, tid & 63);
        int c = blockIdx.x;
        int j0 = c * CHUNK, j1 = min(E, j0 + CHUNK);
        for (int j = j0 + tid; j < j1; j += 256) {
            int d = is64 ? (int)((const long long*)e_raw)[E + j] : e32[E + j];
            atomicAdd(&h[d >> 8], 1);
        }
        __syncthreads();
        for (int b = tid; b < NB; b += 256) histG[(size_t)b * NC + c] = h[b];
        return;
    }
    // ---------- GEMM1 role ----------
    u32* As = smem;                  // [row][k/2], stride 68
    u32* Bs = smem + 64 * 68;        // [col][k/2], stride 68
    const int row0 = ((int)blockIdx.x - NC) * 64;
#pragma unroll
    for (int it = 0; it < 8; it++) {        // stage X, f32 -> bf16
        int i = tid + it * 256;             // 2048 float4
        int r = i >> 5;
        int c4 = (i & 31) << 2;
        int gr = row0 + r;
        float4 v = make_float4(0.f, 0.f, 0.f, 0.f);
        if (gr < n) v = *(const float4*)(X + (size_t)gr * 128 + c4);
        uint2 p;
        p.x = pack2(v.x, v.y);
        p.y = pack2(v.z, v.w);
        *(uint2*)&As[r * 68 + (c4 >> 1)] = p;
    }
#pragma unroll
    for (int it = 0; it < 8; it++) {        // stage WTb (straight copy)
        int i = tid + it * 256;             // 2048 uint4
        int r = i >> 4;
        int c4 = (i & 15) << 2;
        *(uint4*)&Bs[r * 68 + c4] =
            *(const uint4*)((const u32*)WTb + (size_t)r * 64 + c4);
    }
    __syncthreads();

    const int lane = tid & 63;
    const int wave = tid >> 6;
    const int wr = wave >> 1;
    const int wc = wave & 1;
    const int mrow = lane & 15;
    const int quad = lane >> 4;

    floatx4 acc[2][4] = {};
    for (int k0 = 0; k0 < 128; k0 += 32) {
        int koff = (k0 >> 1) + quad * 4;
        short8 a[2], b[4];
#pragma unroll
        for (int i = 0; i < 2; i++)
            a[i] = *(const short8*)&As[((wr * 2 + i) * 16 + mrow) * 68 + koff];
#pragma unroll
        for (int j = 0; j < 4; j++)
            b[j] = *(const short8*)&Bs[((wc * 4 + j) * 16 + mrow) * 68 + koff];
#pragma unroll
        for (int i = 0; i < 2; i++)
#pragma unroll
            for (int j = 0; j < 4; j++)
                acc[i][j] = __builtin_amdgcn_mfma_f32_16x16x32_bf16(
                    a[i], b[j], acc[i][j], 0, 0, 0);
    }
    // slice-major store: slice = gcol>>4 = wc*4+j, intra-slice u16 idx = mrow
#pragma unroll
    for (int i = 0; i < 2; i++) {
        int gr0 = row0 + (wr * 2 + i) * 16 + quad * 4;
#pragma unroll
        for (int j = 0; j < 4; j++) {
            u16* dst = H1s + (size_t)(wc * 4 + j) * ((size_t)n * 16);
#pragma unroll
            for (int rg = 0; rg < 4; rg++) {
                int grow = gr0 + rg;
                if (grow < n)
                    dst[(size_t)grow * 16 + mrow] = f2bf(acc[i][j][rg]);
            }
        }
    }
}

// ---- exclusive scan over histG (NH entries), partial + block sums ----------
__global__ void k_scan1(const int* __restrict__ in, int* __restrict__ out,
                        int* __restrict__ bsum, int n) {
    __shared__ int sh[256];
    int i = blockIdx.x * 256 + threadIdx.x;
    int v = (i < n) ? in[i] : 0;
    sh[threadIdx.x] = v;
    __syncthreads();
    for (int off = 1; off < 256; off <<= 1) {
        int t = (threadIdx.x >= off) ? sh[threadIdx.x - off] : 0;
        __syncthreads();
        sh[threadIdx.x] += t;
        __syncthreads();
    }
    if (i < n) out[i] = sh[threadIdx.x] - v;             // exclusive partial
    if (threadIdx.x == 255) bsum[blockIdx.x] = sh[255];
}

__global__ void k_scan2(int* __restrict__ bsum, int nb) {   // nb <= 1024
    __shared__ int sh[1024];
    int t = threadIdx.x;
    int v = (t < nb) ? bsum[t] : 0;
    sh[t] = v;
    __syncthreads();
    for (int off = 1; off < 1024; off <<= 1) {
        int u = (t >= off) ? sh[t - off] : 0;
        __syncthreads();
        sh[t] += u;
        __syncthreads();
    }
    if (t < nb) bsum[t] = sh[t] - v;                     // exclusive
}

// ---- place edges into bucket runs (LDS cursors; scan fixup inline) ---------
__global__ __launch_bounds__(256) void k_place(const void* __restrict__ e_raw,
                                               const int* __restrict__ histOff,
                                               const int* __restrict__ bsumH,
                                               u32* __restrict__ tmp,
                                               int E, int NB, int NC) {
    __shared__ int cur[512];
    int c = blockIdx.x;
    int t = threadIdx.x;
    for (int b = t; b < NB; b += 256) {
        int idx = b * NC + c;
        cur[b] = histOff[idx] + bsumH[idx >> 8];
    }
    __syncthreads();
    const int* e32 = (const int*)e_raw;
    bool is64 = detect_is64(e32, t & 63);
    int j0 = c * CHUNK, j1 = min(E, j0 + CHUNK);
    for (int j = j0 + t; j < j1; j += 256) {
        int s, d;
        if (is64) {
            s = (int)((const long long*)e_raw)[j];
            d = (int)((const long long*)e_raw)[E + j];
        } else {
            s = e32[j];
            d = e32[E + j];
        }
        int pos = atomicAdd(&cur[d >> 8], 1);
        tmp[pos] = (u32)s | ((u32)(d & 255) << 24);   // s < 2^24
    }
}

// ---- fused deg+sort: per-bucket degree, dinv, exact rowStart, CSR place,
//      plus global 256-bin degree histogram for the scheduling sort ---------
__global__ __launch_bounds__(256) void k_degsort(const u32* __restrict__ tmp,
                                                 const int* __restrict__ histOff,
                                                 const int* __restrict__ bsumH,
                                                 int* __restrict__ degI,
                                                 float* __restrict__ dinv,
                                                 int* __restrict__ rs,
                                                 int* __restrict__ eSrc,
                                                 int* __restrict__ dHist,
                                                 int n, int NB, int NC, int E) {
    __shared__ int cnt[256];
    __shared__ int sh[256];
    __shared__ int cur[256];
    int b = blockIdx.x;
    int t = threadIdx.x;
    cnt[t] = 0;
    __syncthreads();
    int i0 = b * NC;
    int seg0 = histOff[i0] + bsumH[i0 >> 8];
    int seg1 = E;
    if (b + 1 < NB) {
        int i1 = (b + 1) * NC;
        seg1 = histOff[i1] + bsumH[i1 >> 8];
    }
    for (int j = seg0 + t; j < seg1; j += 256) atomicAdd(&cnt[tmp[j] >> 24], 1);
    __syncthreads();
    int v = cnt[t];
    sh[t] = v;
    __syncthreads();
    for (int off = 1; off < 256; off <<= 1) {
        int u = (t >= off) ? sh[t - off] : 0;
        __syncthreads();
        sh[t] += u;
        __syncthreads();
    }
    int myStart = seg0 + sh[t] - v;               // exclusive within bucket
    cur[t] = myStart;
    int node = b * 256 + t;
    if (node < n) {
        degI[node] = v;
        dinv[node] = rsqrtf((float)v + 1.0f);     // +1 self-loop
        rs[node] = myStart;
        atomicAdd(&dHist[min(v, 255)], 1);        // r17 scheduling hist
    }
    __syncthreads();
    for (int j = seg0 + t; j < seg1; j += 256) {
        u32 rec = tmp[j];
        int dl = rec >> 24;
        int s = (int)(rec & 0x00FFFFFFu);
        int pos = atomicAdd(&cur[dl], 1);
        eSrc[pos] = s;
    }
}

// ---- exclusive scan of the 256-bin degree hist (in place -> cursors) -------
__global__ void k_dscan(int* __restrict__ dH) {
    __shared__ int sh[256];
    int t = threadIdx.x;
    int v = dH[t];
    sh[t] = v;
    __syncthreads();
    for (int off = 1; off < 256; off <<= 1) {
        int u = (t >= off) ? sh[t - off] : 0;
        __syncthreads();
        sh[t] += u;
        __syncthreads();
    }
    dH[t] = sh[t] - v;                            // exclusive base = cursor
}

// ---- place nodes into degree-sorted perm (block-local hist + reserve) ------
__global__ __launch_bounds__(256) void k_dperm(const int* __restrict__ degI,
                                               int* __restrict__ dCur,
                                               int* __restrict__ perm, int n) {
    __shared__ int lh[256];
    __shared__ int lc[256];
    int t = threadIdx.x;
    lh[t] = 0;
    __syncthreads();
    int node = blockIdx.x * 256 + t;
    int bin = -1;
    if (node < n) {
        bin = min(degI[node], 255);
        atomicAdd(&lh[bin], 1);
    }
    __syncthreads();
    if (lh[t] > 0) lc[t] = atomicAdd(&dCur[t], lh[t]);
    __syncthreads();
    if (node < n) {
        int pos = atomicAdd(&lc[bin], 1);
        perm[pos] = node;
    }
}

// ---- pack per-edge weight into eSrc top bits: rec = s | round(w*32767)<<17 -
__global__ __launch_bounds__(256) void k_ew(int* __restrict__ eSrc,
                                            const float* __restrict__ dinv,
                                            int E) {
    int i = blockIdx.x * 256 + threadIdx.x;
    if (i >= E) return;
    u32 s = (u32)eSrc[i];
    u32 wq = (u32)__float2int_rn(dinv[s] * 32767.f);
    eSrc[i] = (int)(s | (wq << 17));
}

// ---- XCD-sliced gather, subgroup-per-node, 8-deep pipeline (r13) + perm ----
// Wave = 8 subgroups x 8 lanes; subgroup owns node perm[idx] (degree-sorted
// -> uniform trip counts across the wave, r17). Broadcast edge loads.
__global__ __launch_bounds__(256) void k_gather128(
    const u32* __restrict__ Hb, const int* __restrict__ rs,
    const int* __restrict__ degI, const u32* __restrict__ eW,
    const int* __restrict__ perm, const float* __restrict__ b1,
    u32* __restrict__ outb, int n) {
    const int lane = threadIdx.x & 63;
    const int wave = threadIdx.x >> 6;
    const int g = lane >> 3;               // node subgroup 0..7
    const int l = lane & 7;                // u32 column within 32B slice row
    const int slice = blockIdx.x & 7;
    const int chunk = blockIdx.x >> 3;
    const u32* __restrict__ Hq = Hb + (size_t)slice * ((size_t)n * 8);

    const int idx = chunk * 32 + wave * 8 + g;
    if (idx >= n) return;
    const int node = perm[idx];
    const int start = rs[node];
    const int deg = degI[node];
    float ax = 0.f, ay = 0.f;

    int t = 0;
    if (deg >= 8) {
        u32 r0, r1, r2, r3, r4, r5, r6, r7;
        r0 = eW[start + 0]; r1 = eW[start + 1];
        r2 = eW[start + 2]; r3 = eW[start + 3];
        r4 = eW[start + 4]; r5 = eW[start + 5];
        r6 = eW[start + 6]; r7 = eW[start + 7];
        for (; t + 16 <= deg; t += 8) {
            // dependent gather loads first (their r's are resident) ...
            u32 u0 = Hq[(size_t)(r0 & 0x1FFFFu) * 8 + l];
            u32 u1 = Hq[(size_t)(r1 & 0x1FFFFu) * 8 + l];
            u32 u2 = Hq[(size_t)(r2 & 0x1FFFFu) * 8 + l];
            u32 u3 = Hq[(size_t)(r3 & 0x1FFFFu) * 8 + l];
            u32 u4 = Hq[(size_t)(r4 & 0x1FFFFu) * 8 + l];
            u32 u5 = Hq[(size_t)(r5 & 0x1FFFFu) * 8 + l];
            u32 u6 = Hq[(size_t)(r6 & 0x1FFFFu) * 8 + l];
            u32 u7 = Hq[(size_t)(r7 & 0x1FFFFu) * 8 + l];
            // ... then next batch's independent record loads
            u32 n0 = eW[start + t + 8],  n1 = eW[start + t + 9];
            u32 n2 = eW[start + t + 10], n3 = eW[start + t + 11];
            u32 n4 = eW[start + t + 12], n5 = eW[start + t + 13];
            u32 n6 = eW[start + t + 14], n7 = eW[start + t + 15];
            float w0 = (float)(r0 >> 17), w1 = (float)(r1 >> 17);
            float w2 = (float)(r2 >> 17), w3 = (float)(r3 >> 17);
            float w4 = (float)(r4 >> 17), w5 = (float)(r5 >> 17);
            float w6 = (float)(r6 >> 17), w7 = (float)(r7 >> 17);
            ax = fmaf(w0, bflo(u0), ax); ay = fmaf(w0, bfhi(u0), ay);
            ax = fmaf(w1, bflo(u1), ax); ay = fmaf(w1, bfhi(u1), ay);
            ax = fmaf(w2, bflo(u2), ax); ay = fmaf(w2, bfhi(u2), ay);
            ax = fmaf(w3, bflo(u3), ax); ay = fmaf(w3, bfhi(u3), ay);
            ax = fmaf(w4, bflo(u4), ax); ay = fmaf(w4, bfhi(u4), ay);
            ax = fmaf(w5, bflo(u5), ax); ay = fmaf(w5, bfhi(u5), ay);
            ax = fmaf(w6, bflo(u6), ax); ay = fmaf(w6, bfhi(u6), ay);
            ax = fmaf(w7, bflo(u7), ax); ay = fmaf(w7, bfhi(u7), ay);
            r0 = n0; r1 = n1; r2 = n2; r3 = n3;
            r4 = n4; r5 = n5; r6 = n6; r7 = n7;
        }
        {   // drain: r holds records [t, t+8), all valid
            u32 u0 = Hq[(size_t)(r0 & 0x1FFFFu) * 8 + l];
            u32 u1 = Hq[(size_t)(r1 & 0x1FFFFu) * 8 + l];
            u32 u2 = Hq[(size_t)(r2 & 0x1FFFFu) * 8 + l];
            u32 u3 = Hq[(size_t)(r3 & 0x1FFFFu) * 8 + l];
            u32 u4 = Hq[(size_t)(r4 & 0x1FFFFu) * 8 + l];
            u32 u5 = Hq[(size_t)(r5 & 0x1FFFFu) * 8 + l];
            u32 u6 = Hq[(size_t)(r6 & 0x1FFFFu) * 8 + l];
            u32 u7 = Hq[(size_t)(r7 & 0x1FFFFu) * 8 + l];
            float w0 = (float)(r0 >> 17), w1 = (float)(r1 >> 17);
            float w2 = (float)(r2 >> 17), w3 = (float)(r3 >> 17);
            float w4 = (float)(r4 >> 17), w5 = (float)(r5 >> 17);
            float w6 = (float)(r6 >> 17), w7 = (float)(r7 >> 17);
            ax = fmaf(w0, bflo(u0), ax); ay = fmaf(w0, bfhi(u0), ay);
            ax = fmaf(w1, bflo(u1), ax); ay = fmaf(w1, bfhi(u1), ay);
            ax = fmaf(w2, bflo(u2), ax); ay = fmaf(w2, bfhi(u2), ay);
            ax = fmaf(w3, bflo(u3), ax); ay = fmaf(w3, bfhi(u3), ay);
            ax = fmaf(w4, bflo(u4), ax); ay = fmaf(w4, bfhi(u4), ay);
            ax = fmaf(w5, bflo(u5), ax); ay = fmaf(w5, bfhi(u5), ay);
            ax = fmaf(w6, bflo(u6), ax); ay = fmaf(w6, bfhi(u6), ay);
            ax = fmaf(w7, bflo(u7), ax); ay = fmaf(w7, bfhi(u7), ay);
            t += 8;
        }
    }
    if (t < deg) {                         // masked 8-wide tail (rem 1..7)
        const int dm = deg - 1;
        u32 r0 = eW[start + min(t + 0, dm)], r1 = eW[start + min(t + 1, dm)];
        u32 r2 = eW[start + min(t + 2, dm)], r3 = eW[start + min(t + 3, dm)];
        u32 r4 = eW[start + min(t + 4, dm)], r5 = eW[start + min(t + 5, dm)];
        u32 r6 = eW[start + min(t + 6, dm)];
        u32 u0 = Hq[(size_t)(r0 & 0x1FFFFu) * 8 + l];
        u32 u1 = Hq[(size_t)(r1 & 0x1FFFFu) * 8 + l];
        u32 u2 = Hq[(size_t)(r2 & 0x1FFFFu) * 8 + l];
        u32 u3 = Hq[(size_t)(r3 & 0x1FFFFu) * 8 + l];
        u32 u4 = Hq[(size_t)(r4 & 0x1FFFFu) * 8 + l];
        u32 u5 = Hq[(size_t)(r5 & 0x1FFFFu) * 8 + l];
        u32 u6 = Hq[(size_t)(r6 & 0x1FFFFu) * 8 + l];
        float w0 = (float)(r0 >> 17);
        float w1 = (t + 1 < deg) ? (float)(r1 >> 17) : 0.f;
        float w2 = (t + 2 < deg) ? (float)(r2 >> 17) : 0.f;
        float w3 = (t + 3 < deg) ? (float)(r3 >> 17) : 0.f;
        float w4 = (t + 4 < deg) ? (float)(r4 >> 17) : 0.f;
        float w5 = (t + 5 < deg) ? (float)(r5 >> 17) : 0.f;
        float w6 = (t + 6 < deg) ? (float)(r6 >> 17) : 0.f;
        ax = fmaf(w0, bflo(u0), ax); ay = fmaf(w0, bfhi(u0), ay);
        ax = fmaf(w1, bflo(u1), ax); ay = fmaf(w1, bfhi(u1), ay);
        ax = fmaf(w2, bflo(u2), ax); ay = fmaf(w2, bfhi(u2), ay);
        ax = fmaf(w3, bflo(u3), ax); ay = fmaf(w3, bfhi(u3), ay);
        ax = fmaf(w4, bflo(u4), ax); ay = fmaf(w4, bfhi(u4), ay);
        ax = fmaf(w5, bflo(u5), ax); ay = fmaf(w5, bfhi(u5), ay);
        ax = fmaf(w6, bflo(u6), ax); ay = fmaf(w6, bfhi(u6), ay);
    }
    // w was accumulated as raw 15-bit fixed point: scale once here.
    ax *= (1.f / 32767.f);
    ay *= (1.f / 32767.f);
    const float di = rsqrtf((float)deg + 1.0f);        // == dinv[node]
    const u32 us = Hq[((size_t)node << 3) + l];        // self term (L2-hot)
    const float2 bv = *(const float2*)(b1 + (slice * 8 + l) * 2);
    float inx = fmaf(di, bflo(us), ax);
    float iny = fmaf(di, bfhi(us), ay);
    float rx = fmaxf(fmaf(di, inx, bv.x), 0.f);
    float ry = fmaxf(fmaf(di, iny, bv.y), 0.f);
    outb[(size_t)node * 64 + slice * 8 + l] = pack2(rx, ry);
}

// ---- GEMM2 (MFMA bf16): A1b[n,64]u32 @ W2 -> H2s[n,40] bf16, row*dinv ------
__global__ __launch_bounds__(256) void k_gemm2(const u32* __restrict__ A1b,
                                               const u16* __restrict__ W2Tb,
                                               const float* __restrict__ dinv,
                                               u16* __restrict__ H2s, int n) {
    __shared__ u32 As[64 * 68];
    __shared__ u32 Bs[48 * 68];
    const int tid = threadIdx.x;
    const int row0 = blockIdx.x * 64;
#pragma unroll
    for (int it = 0; it < 4; it++) {        // stage A1 rows (already bf16)
        int i = tid + it * 256;             // 1024 uint4
        int r = i >> 4;
        int c4 = (i & 15) << 2;
        int gr = row0 + r;
        uint4 v = make_uint4(0u, 0u, 0u, 0u);
        if (gr < n) v = *(const uint4*)(A1b + (size_t)gr * 64 + c4);
        *(uint4*)&As[r * 68 + c4] = v;
    }
#pragma unroll
    for (int it = 0; it < 3; it++) {        // stage W2Tb (768 uint4)
        int i = tid + it * 256;
        int r = i >> 4;
        int c4 = (i & 15) << 2;
        *(uint4*)&Bs[r * 68 + c4] =
            *(const uint4*)((const u32*)W2Tb + (size_t)r * 64 + c4);
    }
    __syncthreads();

    const int lane = tid & 63;
    const int wave = tid >> 6;
    const int mrow = lane & 15;
    const int quad = lane >> 4;

    floatx4 acc[3] = {};
    for (int k0 = 0; k0 < 128; k0 += 32) {
        int koff = (k0 >> 1) + quad * 4;
        short8 a = *(const short8*)&As[(wave * 16 + mrow) * 68 + koff];
#pragma unroll
        for (int j = 0; j < 3; j++) {
            short8 b = *(const short8*)&Bs[(j * 16 + mrow) * 68 + koff];
            acc[j] = __builtin_amdgcn_mfma_f32_16x16x32_bf16(a, b, acc[j], 0, 0, 0);
        }
    }
    int gr0 = row0 + wave * 16 + quad * 4;
    float dv[4];
#pragma unroll
    for (int rg = 0; rg < 4; rg++)
        dv[rg] = (gr0 + rg < n) ? dinv[gr0 + rg] : 0.f;
#pragma unroll
    for (int j = 0; j < 3; j++) {
        int gcol = j * 16 + mrow;
        if (gcol < 40) {
#pragma unroll
            for (int rg = 0; rg < 4; rg++) {
                int grow = gr0 + rg;
                if (grow < n)
                    H2s[(size_t)grow * 40 + gcol] = f2bf(dv[rg] * acc[j][rg]);
            }
        }
    }
}

// ---- wave-per-node gather, 40 feats (pre-scaled bf16) + perm ---------------
// 3 subgroups of 20 lanes own contiguous thirds of the edge list; broadcast
// record loads; width-8 decode-early pipeline (r14). node = perm[idx] (r17).
__global__ __launch_bounds__(256) void k_gather40(
    const u32* __restrict__ H2b, const int* __restrict__ rs,
    const int* __restrict__ degI, const u32* __restrict__ eW,
    const int* __restrict__ perm, const float* __restrict__ dinv,
    const float* __restrict__ b2, float* __restrict__ out, int n) {
    const int wave = threadIdx.x >> 6;
    const int lane = threadIdx.x & 63;
    const int idx = blockIdx.x * 4 + wave;
    if (idx >= n) return;
    const int node = perm[idx];
    if (lane >= 60) return;               // subgroup 3 idle
    const int g = lane / 20;              // subgroup 0..2
    const int l = lane - g * 20;          // u32 column 0..19
    const int start = rs[node];
    const int deg = degI[node];
    const int c0 = (deg * g) / 3;         // contiguous third [c0, c1)
    const int c1 = (deg * (g + 1)) / 3;
    const int cnt = c1 - c0;
    const int sb = start + c0;
    float ax = 0.f, ay = 0.f;
    u32 r0, r1, r2, r3, r4, r5, r6, r7;
    u32 u0, u1, u2, u3, u4, u5, u6, u7;
    int t = 0;

#define QH(K) u##K = H2b[(r##K & 0x1FFFFu) * 20 + l];
#define QF(K) r##K = eW[bq + K];
#define QA(K) ax += bflo(u##K); ay += bfhi(u##K);

    if (cnt >= 8) {
        int bq = sb;
        REP8(QF)
        for (; t + 16 <= cnt; t += 8) {
            REP8(QH)
            bq = sb + t + 8;
            REP8(QF)
            REP8(QA)
        }
        REP8(QH)
        REP8(QA)
        t += 8;
    }
    if (t < cnt) {                        // masked tail, rem 1..7
        const int bq = sb + t;
        const int rm = cnt - t - 1;       // 0..6
#define QTF(K) r##K = eW[bq + min(K, rm)];
#define QTM(K) if (K > rm) u##K = 0u;
        REP7(QTF)
        REP7(QH)
        REP7(QTM)
        REP7(QA)
#undef QTF
#undef QTM
    }
#undef QH
#undef QF
#undef QA
    float x1 = __shfl(ax, (lane + 20) & 63), y1 = __shfl(ay, (lane + 20) & 63);
    float x2 = __shfl(ax, (lane + 40) & 63), y2 = __shfl(ay, (lane + 40) & 63);
    if (lane < 20) {
        float di = dinv[node];
        u32 u = H2b[(size_t)node * 20 + l];
        float2 bv = *(const float2*)(b2 + l * 2);
        float ox = fmaf(di, ax + x1 + x2 + bflo(u), bv.x);
        float oy = fmaf(di, ay + y1 + y2 + bfhi(u), bv.y);
        *(float2*)(out + (size_t)node * 40 + l * 2) = make_float2(ox, oy);
    }
}

extern "C" void kernel_launch(void* const* d_in, const int* in_sizes, int n_in,
                              void* d_out, int out_size, void* d_ws, size_t ws_size,
                              hipStream_t stream) {
    const float* x  = (const float*)d_in[0];
    const void*  e  = d_in[1];
    const float* W1 = (const float*)d_in[2];
    const float* b1 = (const float*)d_in[3];
    const float* W2 = (const float*)d_in[4];
    const float* b2 = (const float*)d_in[5];
    float* out = (float*)d_out;

    const int n = in_sizes[0] / 128;
    const int E = in_sizes[1] / 2;
    const int NB = (n + 255) / 256;          // node buckets (391)
    const int NC = (E + CHUNK - 1) / CHUNK;  // edge chunks (391)
    const int NH = NB * NC;                  // histogram entries (~153k)
    const int nbH = (NH + 255) / 256;        // scan blocks (<=1024 for scan2)
    const int G1 = (n + 63) / 64;            // gemm1 blocks

    // workspace
    int*   degI    = (int*)d_ws;                     // n
    int*   rs      = degI + n;                       // n
    int*   bsumH   = rs + n;                         // 1024
    float* dinv    = (float*)(bsumH + 1024);         // n
    int*   dHist   = (int*)(dinv + n);               // 256 (hist -> cursor)
    int*   perm    = dHist + 256;                    // n (deg-sorted nodes)
    int*   histG   = perm + n;                       // NH
    int*   histOff = histG + NH;                     // NH
    size_t off = (size_t)((char*)(histOff + NH) - (char*)d_ws);
    off = (off + 15) & ~(size_t)15;
    u16*   WTb    = (u16*)((char*)d_ws + off);       // 128*128 bf16 (W1^T)
    u16*   W2Tb   = WTb + 16384;                     // 48*128 bf16 (W2^T pad)
    off = (size_t)((char*)(W2Tb + 6144) - (char*)d_ws);
    off = (off + 15) & ~(size_t)15;
    u32*   tmp    = (u32*)((char*)d_ws + off);       // E bucket records
    int*   eSrc   = (int*)(tmp + (size_t)E);         // E packed (s|wq<<17)
    u16*   H1s    = (u16*)(eSrc + (size_t)E);        // n*128 bf16, SLICE-MAJOR
    u32*   H1b    = (u32*)H1s;                       // same memory, [8][n][8] u32
    u32*   A1b    = (u32*)(H1s + (size_t)n * 128);   // n*64 u32 (relu out)
    u16*   H2s    = (u16*)(A1b + (size_t)n * 64);    // n*40 bf16 (pre-scaled)
    u32*   H2b    = (u32*)H2s;

    k_prepW<<<89, 256, 0, stream>>>(W1, W2, WTb, W2Tb, dHist);
    k_front<<<NC + G1, 256, 0, stream>>>(e, E, NC, NB, histG, x, WTb, H1s, n);

    k_scan1<<<nbH, 256, 0, stream>>>(histG, histOff, bsumH, NH);
    k_scan2<<<1, 1024, 0, stream>>>(bsumH, nbH);
    k_place<<<NC, 256, 0, stream>>>(e, histOff, bsumH, tmp, E, NB, NC);

    k_degsort<<<NB, 256, 0, stream>>>(tmp, histOff, bsumH, degI, dinv, rs,
                                      eSrc, dHist, n, NB, NC, E);
    k_dscan<<<1, 256, 0, stream>>>(dHist);
    k_dperm<<<NB, 256, 0, stream>>>(degI, dHist, perm, n);
    k_ew<<<(E + 255) / 256, 256, 0, stream>>>(eSrc, dinv, E);

    k_gather128<<<8 * ((n + 31) / 32), 256, 0, stream>>>(H1b, rs, degI,
                                                         (const u32*)eSrc,
                                                         perm, b1, A1b, n);
    k_gemm2<<<(n + 63) / 64, 256, 0, stream>>>(A1b, W2Tb, dinv, H2s, n);
    k_gather40<<<(n + 3) / 4, 256, 0, stream>>>(H2b, rs, degI, (const u32*)eSrc,
                                                perm, dinv, b2, out, n);
}

// Round 8
// 299.433 us; speedup vs baseline: 2.0019x; 2.0019x over previous
//
#include <hip/hip_runtime.h>

// ---------------------------------------------------------------------------
// 2-layer GCN forward, 9-launch pipeline (r18 = r0 baseline + sliced gather40).
// prepW -> front(hist+gemm1 fused) -> scan1 -> scan2 -> place -> degsort
// -> gather128 -> gemm2 -> gather40.
// ROOFLINE NOTE (r18): pull-gather must move E*256B = 3.28GB through the
// cache hierarchy; best attainable mix ~35-40 TB/s => ~90us floor. r0's
// gather128 (87.6us, 16-way shfl MLP, unsliced) is AT that floor; sliced
// variants (r13/r14: 97-102us) sit exactly on the all-L2 34.5TB/s roofline.
// So gather128 reverts to r0. The recoverable chunk is gather40: H2=8MB
// doesn't fit a 4MB XCD L2 -> slice-major [2][n][10]u32 (4MB/slice,
// slice=blockIdx&1 rides XCD round-robin) + r13-proven subgroup-per-node
// 8-deep broadcast pipeline (floor ~20us vs latency-bound before).
// r15 lesson: LDS-atomic push = op-count wall. r16: glds+shfl loses.
// r17 lesson: global atomics onto 256 ints = 4 cache lines serialize
// chip-wide (270us); scheduling-sort abandoned.
// ---------------------------------------------------------------------------

typedef unsigned int u32;
typedef unsigned short u16;
typedef __attribute__((ext_vector_type(8))) short short8;
typedef __attribute__((ext_vector_type(4))) float floatx4;

#define CHUNK 4096            // edges per histogram/place block

#define REP7(M)  M(0) M(1) M(2) M(3) M(4) M(5) M(6)
#define REP8(M)  M(0) M(1) M(2) M(3) M(4) M(5) M(6) M(7)

static __device__ inline u16 f2bf(float f) {
    u32 u = __float_as_uint(f);
    return (u16)((u + 0x7FFFu + ((u >> 16) & 1u)) >> 16);   // RNE
}
static __device__ inline u32 pack2(float a, float b) {
    return (u32)f2bf(a) | ((u32)f2bf(b) << 16);
}
static __device__ inline float bflo(u32 u) { return __uint_as_float(u << 16); }
static __device__ inline float bfhi(u32 u) { return __uint_as_float(u & 0xffff0000u); }

// wave-local int64-vs-int32 storage detection: sample 64 odd int32 slots of
// the first 64 index values; all-zero => int64 (high words), else int32.
static __device__ inline bool detect_is64(const int* e32, int lane) {
    bool nz = e32[2 * lane + 1] != 0;
    return __ballot(nz) == 0ull;
}

// ---- W1 [128,128] -> WTb [c][k] bf16; W2 [128,40] -> W2Tb [48][128] bf16 ---
__global__ void k_prepW(const float* __restrict__ W1, const float* __restrict__ W2,
                        u16* __restrict__ WTb, u16* __restrict__ W2Tb) {
    int id = blockIdx.x * 256 + threadIdx.x;
    if (id < 16384) {
        int k = id >> 7, c = id & 127;           // W1[k][c]
        WTb[c * 128 + k] = f2bf(W1[id]);
    } else {
        int id2 = id - 16384;
        if (id2 < 6144) {                        // 48 x 128, zero-pad cols 40+
            int c = id2 >> 7, k = id2 & 127;
            W2Tb[id2] = f2bf(c < 40 ? W2[k * 40 + c] : 0.f);
        }
    }
}

// ---- fused front: blocks [0,NC) = per-chunk bucket histogram,
//      blocks [NC, NC+G1) = GEMM1 (MFMA, unscaled bf16 out) -----------------
__global__ __launch_bounds__(256) void k_front(const void* __restrict__ e_raw,
                                               int E, int NC, int NB,
                                               int* __restrict__ histG,
                                               const float* __restrict__ X,
                                               const u16* __restrict__ WTb,
                                               u16* __restrict__ H1s, int n) {
    __shared__ u32 smem[64 * 68 + 128 * 68];     // 52,224 B, shared by roles
    const int tid = threadIdx.x;
    if ((int)blockIdx.x < NC) {
        // ---------- histogram role ----------
        int* h = (int*)smem;
        h[tid] = 0; h[tid + 256] = 0;
        __syncthreads();
        const int* e32 = (const int*)e_raw;
        bool is64 = detect_is64(e32, tid & 63);
        int c = blockIdx.x;
        int j0 = c * CHUNK, j1 = min(E, j0 + CHUNK);
        for (int j = j0 + tid; j < j1; j += 256) {
            int d = is64 ? (int)((const long long*)e_raw)[E + j] : e32[E + j];
            atomicAdd(&h[d >> 8], 1);
        }
        __syncthreads();
        for (int b = tid; b < NB; b += 256) histG[(size_t)b * NC + c] = h[b];
        return;
    }
    // ---------- GEMM1 role ----------
    u32* As = smem;                  // [row][k/2], stride 68
    u32* Bs = smem + 64 * 68;        // [col][k/2], stride 68
    const int row0 = ((int)blockIdx.x - NC) * 64;
#pragma unroll
    for (int it = 0; it < 8; it++) {        // stage X, f32 -> bf16
        int i = tid + it * 256;             // 2048 float4
        int r = i >> 5;
        int c4 = (i & 31) << 2;
        int gr = row0 + r;
        float4 v = make_float4(0.f, 0.f, 0.f, 0.f);
        if (gr < n) v = *(const float4*)(X + (size_t)gr * 128 + c4);
        uint2 p;
        p.x = pack2(v.x, v.y);
        p.y = pack2(v.z, v.w);
        *(uint2*)&As[r * 68 + (c4 >> 1)] = p;
    }
#pragma unroll
    for (int it = 0; it < 8; it++) {        // stage WTb (straight copy)
        int i = tid + it * 256;             // 2048 uint4
        int r = i >> 4;
        int c4 = (i & 15) << 2;
        *(uint4*)&Bs[r * 68 + c4] =
            *(const uint4*)((const u32*)WTb + (size_t)r * 64 + c4);
    }
    __syncthreads();

    const int lane = tid & 63;
    const int wave = tid >> 6;
    const int wr = wave >> 1;
    const int wc = wave & 1;
    const int mrow = lane & 15;
    const int quad = lane >> 4;

    floatx4 acc[2][4] = {};
    for (int k0 = 0; k0 < 128; k0 += 32) {
        int koff = (k0 >> 1) + quad * 4;
        short8 a[2], b[4];
#pragma unroll
        for (int i = 0; i < 2; i++)
            a[i] = *(const short8*)&As[((wr * 2 + i) * 16 + mrow) * 68 + koff];
#pragma unroll
        for (int j = 0; j < 4; j++)
            b[j] = *(const short8*)&Bs[((wc * 4 + j) * 16 + mrow) * 68 + koff];
#pragma unroll
        for (int i = 0; i < 2; i++)
#pragma unroll
            for (int j = 0; j < 4; j++)
                acc[i][j] = __builtin_amdgcn_mfma_f32_16x16x32_bf16(
                    a[i], b[j], acc[i][j], 0, 0, 0);
    }
#pragma unroll
    for (int i = 0; i < 2; i++) {
        int gr0 = row0 + (wr * 2 + i) * 16 + quad * 4;
#pragma unroll
        for (int j = 0; j < 4; j++) {
            int gcol = (wc * 4 + j) * 16 + mrow;
#pragma unroll
            for (int rg = 0; rg < 4; rg++) {
                int grow = gr0 + rg;
                if (grow < n)
                    H1s[(size_t)grow * 128 + gcol] = f2bf(acc[i][j][rg]);
            }
        }
    }
}

// ---- exclusive scan over histG (NH entries), partial + block sums ----------
__global__ void k_scan1(const int* __restrict__ in, int* __restrict__ out,
                        int* __restrict__ bsum, int n) {
    __shared__ int sh[256];
    int i = blockIdx.x * 256 + threadIdx.x;
    int v = (i < n) ? in[i] : 0;
    sh[threadIdx.x] = v;
    __syncthreads();
    for (int off = 1; off < 256; off <<= 1) {
        int t = (threadIdx.x >= off) ? sh[threadIdx.x - off] : 0;
        __syncthreads();
        sh[threadIdx.x] += t;
        __syncthreads();
    }
    if (i < n) out[i] = sh[threadIdx.x] - v;             // exclusive partial
    if (threadIdx.x == 255) bsum[blockIdx.x] = sh[255];
}

__global__ void k_scan2(int* __restrict__ bsum, int nb) {   // nb <= 1024
    __shared__ int sh[1024];
    int t = threadIdx.x;
    int v = (t < nb) ? bsum[t] : 0;
    sh[t] = v;
    __syncthreads();
    for (int off = 1; off < 1024; off <<= 1) {
        int u = (t >= off) ? sh[t - off] : 0;
        __syncthreads();
        sh[t] += u;
        __syncthreads();
    }
    if (t < nb) bsum[t] = sh[t] - v;                     // exclusive
}

// ---- place edges into bucket runs (LDS cursors; scan fixup inline) ---------
__global__ __launch_bounds__(256) void k_place(const void* __restrict__ e_raw,
                                               const int* __restrict__ histOff,
                                               const int* __restrict__ bsumH,
                                               u32* __restrict__ tmp,
                                               int E, int NB, int NC) {
    __shared__ int cur[512];
    int c = blockIdx.x;
    int t = threadIdx.x;
    for (int b = t; b < NB; b += 256) {
        int idx = b * NC + c;
        cur[b] = histOff[idx] + bsumH[idx >> 8];
    }
    __syncthreads();
    const int* e32 = (const int*)e_raw;
    bool is64 = detect_is64(e32, t & 63);
    int j0 = c * CHUNK, j1 = min(E, j0 + CHUNK);
    for (int j = j0 + t; j < j1; j += 256) {
        int s, d;
        if (is64) {
            s = (int)((const long long*)e_raw)[j];
            d = (int)((const long long*)e_raw)[E + j];
        } else {
            s = e32[j];
            d = e32[E + j];
        }
        int pos = atomicAdd(&cur[d >> 8], 1);
        tmp[pos] = (u32)s | ((u32)(d & 255) << 24);   // s < 2^24
    }
}

// ---- fused deg+sort: per-bucket degree, dinv, exact rowStart, then place
//      records into exact per-node CSR order (all LDS-cursor) ---------------
__global__ __launch_bounds__(256) void k_degsort(const u32* __restrict__ tmp,
                                                 const int* __restrict__ histOff,
                                                 const int* __restrict__ bsumH,
                                                 int* __restrict__ degI,
                                                 float* __restrict__ dinv,
                                                 int* __restrict__ rs,
                                                 int* __restrict__ eSrc,
                                                 int n, int NB, int NC, int E) {
    __shared__ int cnt[256];
    __shared__ int sh[256];
    __shared__ int cur[256];
    int b = blockIdx.x;
    int t = threadIdx.x;
    cnt[t] = 0;
    __syncthreads();
    int i0 = b * NC;
    int seg0 = histOff[i0] + bsumH[i0 >> 8];
    int seg1 = E;
    if (b + 1 < NB) {
        int i1 = (b + 1) * NC;
        seg1 = histOff[i1] + bsumH[i1 >> 8];
    }
    for (int j = seg0 + t; j < seg1; j += 256) atomicAdd(&cnt[tmp[j] >> 24], 1);
    __syncthreads();
    int v = cnt[t];
    sh[t] = v;
    __syncthreads();
    for (int off = 1; off < 256; off <<= 1) {
        int u = (t >= off) ? sh[t - off] : 0;
        __syncthreads();
        sh[t] += u;
        __syncthreads();
    }
    int myStart = seg0 + sh[t] - v;               // exclusive within bucket
    cur[t] = myStart;
    int node = b * 256 + t;
    if (node < n) {
        degI[node] = v;
        dinv[node] = rsqrtf((float)v + 1.0f);     // +1 self-loop
        rs[node] = myStart;
    }
    __syncthreads();
    for (int j = seg0 + t; j < seg1; j += 256) {
        u32 rec = tmp[j];
        int dl = rec >> 24;
        int s = (int)(rec & 0x00FFFFFFu);
        int pos = atomicAdd(&cur[dl], 1);
        eSrc[pos] = s;
    }
}

// ---- wave-per-node gather, 128 feats (unscaled bf16 rows, per-edge dinv) ---
// out = relu(dinv_d*(sum dinv_s*h_s + dinv_d*h_d) + b1), packed bf16x2
// 16-way MLP unroll (r0 structure: AT the ~90us bytes/BW floor; keep).
__global__ __launch_bounds__(256) void k_gather128(
    const u32* __restrict__ Hb, const int* __restrict__ rs,
    const int* __restrict__ degI, const int* __restrict__ eSrc,
    const float* __restrict__ dinv, const float* __restrict__ b1,
    u32* __restrict__ outb, int n) {
    int wave = threadIdx.x >> 6;
    int lane = threadIdx.x & 63;
    int node = blockIdx.x * 4 + wave;
    if (node >= n) return;
    int start = rs[node];
    int deg = degI[node];
    float ax = 0.f, ay = 0.f;
    for (int base = 0; base < deg; base += 64) {
        int mS = 0;
        float mW = 0.f;
        if (base + lane < deg) { mS = eSrc[start + base + lane]; mW = dinv[mS]; }
        int cnt = min(64, deg - base);
        int t = 0;
        for (; t + 16 <= cnt; t += 16) {     // 16-way MLP
            int ss[16];
            float ww[16];
            u32 uu[16];
#pragma unroll
            for (int q = 0; q < 16; q++) {
                ss[q] = __shfl(mS, t + q);
                ww[q] = __shfl(mW, t + q);
            }
#pragma unroll
            for (int q = 0; q < 16; q++) uu[q] = Hb[(size_t)ss[q] * 64 + lane];
#pragma unroll
            for (int q = 0; q < 16; q++) {
                ax = fmaf(ww[q], bflo(uu[q]), ax);
                ay = fmaf(ww[q], bfhi(uu[q]), ay);
            }
        }
        for (; t + 4 <= cnt; t += 4) {       // 4-way tail
            int s0 = __shfl(mS, t + 0), s1 = __shfl(mS, t + 1);
            int s2 = __shfl(mS, t + 2), s3 = __shfl(mS, t + 3);
            float w0 = __shfl(mW, t + 0), w1 = __shfl(mW, t + 1);
            float w2 = __shfl(mW, t + 2), w3 = __shfl(mW, t + 3);
            u32 u0 = Hb[(size_t)s0 * 64 + lane];
            u32 u1 = Hb[(size_t)s1 * 64 + lane];
            u32 u2 = Hb[(size_t)s2 * 64 + lane];
            u32 u3 = Hb[(size_t)s3 * 64 + lane];
            ax = fmaf(w0, bflo(u0), ax); ay = fmaf(w0, bfhi(u0), ay);
            ax = fmaf(w1, bflo(u1), ax); ay = fmaf(w1, bfhi(u1), ay);
            ax = fmaf(w2, bflo(u2), ax); ay = fmaf(w2, bfhi(u2), ay);
            ax = fmaf(w3, bflo(u3), ax); ay = fmaf(w3, bfhi(u3), ay);
        }
        for (; t < cnt; t++) {
            int s = __shfl(mS, t);
            float w = __shfl(mW, t);
            u32 u = Hb[(size_t)s * 64 + lane];
            ax = fmaf(w, bflo(u), ax); ay = fmaf(w, bfhi(u), ay);
        }
    }
    float di = dinv[node];
    u32 us = Hb[(size_t)node * 64 + lane];   // self term (unscaled)
    float inx = fmaf(di, bflo(us), ax);
    float iny = fmaf(di, bfhi(us), ay);
    float2 bv = *(const float2*)(b1 + lane * 2);
    float rx = fmaxf(fmaf(di, inx, bv.x), 0.f);
    float ry = fmaxf(fmaf(di, iny, bv.y), 0.f);
    outb[(size_t)node * 64 + lane] = pack2(rx, ry);
}

// ---- GEMM2 (MFMA bf16): A1b[n,64]u32 @ W2 -> H2 SLICE-MAJOR [2][n][20]u16,
//      row*dinv (r18: 4MB/slice fits a per-XCD L2 for the sliced gather40) --
__global__ __launch_bounds__(256) void k_gemm2(const u32* __restrict__ A1b,
                                               const u16* __restrict__ W2Tb,
                                               const float* __restrict__ dinv,
                                               u16* __restrict__ H2s, int n) {
    __shared__ u32 As[64 * 68];
    __shared__ u32 Bs[48 * 68];
    const int tid = threadIdx.x;
    const int row0 = blockIdx.x * 64;
#pragma unroll
    for (int it = 0; it < 4; it++) {        // stage A1 rows (already bf16)
        int i = tid + it * 256;             // 1024 uint4
        int r = i >> 4;
        int c4 = (i & 15) << 2;
        int gr = row0 + r;
        uint4 v = make_uint4(0u, 0u, 0u, 0u);
        if (gr < n) v = *(const uint4*)(A1b + (size_t)gr * 64 + c4);
        *(uint4*)&As[r * 68 + c4] = v;
    }
#pragma unroll
    for (int it = 0; it < 3; it++) {        // stage W2Tb (768 uint4)
        int i = tid + it * 256;
        int r = i >> 4;
        int c4 = (i & 15) << 2;
        *(uint4*)&Bs[r * 68 + c4] =
            *(const uint4*)((const u32*)W2Tb + (size_t)r * 64 + c4);
    }
    __syncthreads();

    const int lane = tid & 63;
    const int wave = tid >> 6;
    const int mrow = lane & 15;
    const int quad = lane >> 4;

    floatx4 acc[3] = {};
    for (int k0 = 0; k0 < 128; k0 += 32) {
        int koff = (k0 >> 1) + quad * 4;
        short8 a = *(const short8*)&As[(wave * 16 + mrow) * 68 + koff];
#pragma unroll
        for (int j = 0; j < 3; j++) {
            short8 b = *(const short8*)&Bs[(j * 16 + mrow) * 68 + koff];
            acc[j] = __builtin_amdgcn_mfma_f32_16x16x32_bf16(a, b, acc[j], 0, 0, 0);
        }
    }
    int gr0 = row0 + wave * 16 + quad * 4;
    float dv[4];
#pragma unroll
    for (int rg = 0; rg < 4; rg++)
        dv[rg] = (gr0 + rg < n) ? dinv[gr0 + rg] : 0.f;
#pragma unroll
    for (int j = 0; j < 3; j++) {
        int gcol = j * 16 + mrow;
        if (gcol < 40) {
            int sl = (gcol >= 20) ? 1 : 0;
            int c = gcol - sl * 20;
            u16* dstp = H2s + (size_t)sl * ((size_t)n * 20);
#pragma unroll
            for (int rg = 0; rg < 4; rg++) {
                int grow = gr0 + rg;
                if (grow < n)
                    dstp[(size_t)grow * 20 + c] = f2bf(dv[rg] * acc[j][rg]);
            }
        }
    }
}

// ---- XCD-sliced gather40 (r18): slice = blockIdx&1, H2 slice = 4MB -> L2 --
// Wave = 6 subgroups x 10 lanes (60 active); subgroup owns ONE node, lane
// owns u32 column l of the 40B slice row. Broadcast record loads, 8-deep
// rotation pipeline (r13-proven shape, weightless: H2 pre-scaled by dinv).
// out = dinv_d * (sum h'_s + h'_d) + b2, f32.
__global__ __launch_bounds__(256) void k_gather40(
    const u32* __restrict__ H2b, const int* __restrict__ rs,
    const int* __restrict__ degI, const int* __restrict__ eSrc,
    const float* __restrict__ dinv, const float* __restrict__ b2,
    float* __restrict__ out, int n) {
    const int lane = threadIdx.x & 63;
    const int wave = threadIdx.x >> 6;
    const int g = lane / 10;               // subgroup 0..5; 6 = idle lanes
    const int l = lane - g * 10;           // u32 column 0..9
    const int slice = blockIdx.x & 1;
    const int chunk = blockIdx.x >> 1;
    if (g >= 6) return;
    const u32* __restrict__ Hs = H2b + (size_t)slice * ((size_t)n * 10);

    const int node = chunk * 24 + wave * 6 + g;
    if (node >= n) return;
    const int start = rs[node];
    const int deg = degI[node];
    float ax = 0.f, ay = 0.f;
    u32 r0, r1, r2, r3, r4, r5, r6, r7;
    u32 u0, u1, u2, u3, u4, u5, u6, u7;
    int t = 0;

#define PH(K) u##K = Hs[(size_t)r##K * 10 + l];
#define PF(K) r##K = (u32)eSrc[bq + K];
#define PA(K) ax += bflo(u##K); ay += bfhi(u##K);

    if (deg >= 8) {
        int bq = start;
        REP8(PF)
        for (; t + 16 <= deg; t += 8) {
            REP8(PH)                        // 8 gathers (records resident)
            bq = start + t + 8;
            REP8(PF)                        // 8 refills stay in flight
            REP8(PA)
        }
        REP8(PH)                            // drain
        REP8(PA)
        t += 8;
    }
    if (t < deg) {                          // masked tail, rem 1..7
        const int bq = start + t;
        const int rm = deg - t - 1;         // 0..6
#define PTF(K) r##K = (u32)eSrc[bq + min(K, rm)];
#define PTA(K) if (K <= rm) { ax += bflo(u##K); ay += bfhi(u##K); }
        REP7(PTF)
        REP7(PH)
        REP7(PTA)
#undef PTF
#undef PTA
    }
#undef PH
#undef PF
#undef PA
    const float di = dinv[node];
    const u32 us = Hs[(size_t)node * 10 + l];          // pre-scaled self term
    const float2 bv = *(const float2*)(b2 + (slice * 10 + l) * 2);
    float ox = fmaf(di, ax + bflo(us), bv.x);
    float oy = fmaf(di, ay + bfhi(us), bv.y);
    *(float2*)(out + (size_t)node * 40 + (slice * 10 + l) * 2) =
        make_float2(ox, oy);
}

extern "C" void kernel_launch(void* const* d_in, const int* in_sizes, int n_in,
                              void* d_out, int out_size, void* d_ws, size_t ws_size,
                              hipStream_t stream) {
    const float* x  = (const float*)d_in[0];
    const void*  e  = d_in[1];
    const float* W1 = (const float*)d_in[2];
    const float* b1 = (const float*)d_in[3];
    const float* W2 = (const float*)d_in[4];
    const float* b2 = (const float*)d_in[5];
    float* out = (float*)d_out;

    const int n = in_sizes[0] / 128;
    const int E = in_sizes[1] / 2;
    const int NB = (n + 255) / 256;          // node buckets (391)
    const int NC = (E + CHUNK - 1) / CHUNK;  // edge chunks (391)
    const int NH = NB * NC;                  // histogram entries (~153k)
    const int nbH = (NH + 255) / 256;        // scan blocks (<=1024 for scan2)
    const int G1 = (n + 63) / 64;            // gemm1 blocks

    // workspace
    int*   degI    = (int*)d_ws;                     // n
    int*   rs      = degI + n;                       // n
    int*   bsumH   = rs + n;                         // 1024
    float* dinv    = (float*)(bsumH + 1024);         // n
    int*   histG   = (int*)(dinv + n);               // NH
    int*   histOff = histG + NH;                     // NH
    size_t off = (size_t)((char*)(histOff + NH) - (char*)d_ws);
    off = (off + 15) & ~(size_t)15;
    u16*   WTb    = (u16*)((char*)d_ws + off);       // 128*128 bf16 (W1^T)
    u16*   W2Tb   = WTb + 16384;                     // 48*128 bf16 (W2^T pad)
    off = (size_t)((char*)(W2Tb + 6144) - (char*)d_ws);
    off = (off + 15) & ~(size_t)15;
    u32*   tmp    = (u32*)((char*)d_ws + off);       // E bucket records
    int*   eSrc   = (int*)(tmp + (size_t)E);         // E CSR src indices
    u16*   H1s    = (u16*)(eSrc + (size_t)E);        // n*128 bf16 (unscaled)
    u32*   H1b    = (u32*)H1s;                       // same memory, [n,64] u32
    u32*   A1b    = (u32*)(H1s + (size_t)n * 128);   // n*64 u32 (relu out)
    u16*   H2s    = (u16*)(A1b + (size_t)n * 64);    // [2][n][20] bf16 (scaled)
    u32*   H2b    = (u32*)H2s;                       // u32 view [2][n][10]

    k_prepW<<<88, 256, 0, stream>>>(W1, W2, WTb, W2Tb);
    k_front<<<NC + G1, 256, 0, stream>>>(e, E, NC, NB, histG, x, WTb, H1s, n);

    k_scan1<<<nbH, 256, 0, stream>>>(histG, histOff, bsumH, NH);
    k_scan2<<<1, 1024, 0, stream>>>(bsumH, nbH);
    k_place<<<NC, 256, 0, stream>>>(e, histOff, bsumH, tmp, E, NB, NC);

    k_degsort<<<NB, 256, 0, stream>>>(tmp, histOff, bsumH, degI, dinv, rs,
                                      eSrc, n, NB, NC, E);

    k_gather128<<<(n + 3) / 4, 256, 0, stream>>>(H1b, rs, degI, eSrc, dinv,
                                                 b1, A1b, n);
    k_gemm2<<<(n + 63) / 64, 256, 0, stream>>>(A1b, W2Tb, dinv, H2s, n);
    k_gather40<<<2 * ((n + 23) / 24), 256, 0, stream>>>(H2b, rs, degI, eSrc,
                                                        dinv, b2, out, n);
}